// Round 1
// baseline (195.244 us; speedup 1.0000x reference)
//
#include <hip/hip_runtime.h>
#include <hip/hip_bf16.h>
#include <float.h>

#define B_    32
#define T_    16
#define DIN   768
#define DSAE  16384
#define K_    32
#define KTOT  2304   // DIN*3
#define KC    64
#define BN    32
#define TD    12288  // T_*DIN

// ---------------- Kernel 1: prep — build A_T[k][b], k = d*3+j ----------------
// u0 = S - x[b,15,d] ; u1 = S ; u2 = S - x[b,0,d]   (S = sum_t x[b,t,d])
__global__ __launch_bounds__(256) void prep_kernel(const float* __restrict__ x,
                                                   float* __restrict__ A_T) {
    int g = blockIdx.x * 256 + threadIdx.x;      // 0..24575
    int b = g / DIN;
    int d = g - b * DIN;
    const float* xp = x + (size_t)b * TD + d;
    float S = 0.f;
    float x0 = xp[0];
    float xl = xp[15 * DIN];
    #pragma unroll
    for (int t = 0; t < T_; ++t) S += xp[t * DIN];
    int base = d * 96 + b;                       // (d*3+j)*32 + b
    A_T[base]      = S - xl;                     // j=0
    A_T[base + 32] = S;                          // j=1
    A_T[base + 64] = S - x0;                     // j=2
}

// ---------------- Kernel 2: encode GEMM  pre[b][s] = A·Wᵀ + b_enc ----------------
// 512 blocks x 256 thr; block = 32 s-rows, all 32 b. thread: sl=tid&31 (1 s), bg=tid>>5 (4 b)
__global__ __launch_bounds__(256, 8) void enc_gemm_kernel(
    const float* __restrict__ W,      // conv_w flattened (DSAE x KTOT)
    const float* __restrict__ A_T,    // (KTOT x 32)
    const float* __restrict__ b_enc,
    float* __restrict__ pre)          // (32 x DSAE)  [z region]
{
    __shared__ float  Wt[BN * 65];    // [s][k], pad 65 -> conflict-free reads
    __shared__ float4 At4[KC * 8];    // [kk][b/4]

    const int tid = threadIdx.x;
    const int s0  = blockIdx.x * BN;
    const int sl  = tid & 31;
    const int bg  = tid >> 5;         // 0..7

    float4 acc = {0.f, 0.f, 0.f, 0.f};

    for (int kc = 0; kc < KTOT; kc += KC) {
        __syncthreads();
        // stage W tile: 32 rows x 64 k = 2048 floats (2 float4 / thread, coalesced)
        #pragma unroll
        for (int i = 0; i < 2; ++i) {
            int f4  = tid + 256 * i;              // 0..511
            int row = f4 >> 4;                    // 16 float4 per row
            int c4  = (f4 & 15) << 2;
            float4 v = *(const float4*)&W[(size_t)(s0 + row) * KTOT + kc + c4];
            Wt[row * 65 + c4 + 0] = v.x;
            Wt[row * 65 + c4 + 1] = v.y;
            Wt[row * 65 + c4 + 2] = v.z;
            Wt[row * 65 + c4 + 3] = v.w;
        }
        // stage A tile: 64 kk x 32 b = 2048 floats (contiguous, coalesced)
        {
            const float4* src = (const float4*)&A_T[kc * 32];
            At4[tid * 2]     = src[tid * 2];
            At4[tid * 2 + 1] = src[tid * 2 + 1];
        }
        __syncthreads();

        #pragma unroll 16
        for (int kk = 0; kk < KC; ++kk) {
            float  w = Wt[sl * 65 + kk];          // 32 distinct banks, broadcast x2
            float4 a = At4[kk * 8 + bg];          // wave-uniform -> broadcast
            acc.x += w * a.x;
            acc.y += w * a.y;
            acc.z += w * a.z;
            acc.w += w * a.w;
        }
    }

    const int s  = s0 + sl;
    const float be = b_enc[s];
    const int b0 = bg * 4;
    pre[(size_t)(b0 + 0) * DSAE + s] = acc.x + be;
    pre[(size_t)(b0 + 1) * DSAE + s] = acc.y + be;
    pre[(size_t)(b0 + 2) * DSAE + s] = acc.z + be;
    pre[(size_t)(b0 + 3) * DSAE + s] = acc.w + be;
}

// ---------------- Kernel 3: top-k (iterative argmax, exact tie-break = lower idx) ----------------
// one block per batch row; row lives in registers (64 f32/thread)
__global__ __launch_bounds__(256, 1) void topk_kernel(
    float* __restrict__ z,            // in: pre row-major (32 x DSAE); out: sparse z
    float* __restrict__ sel_val,
    int*   __restrict__ sel_idx)
{
    __shared__ float wv[4];
    __shared__ int   wi[4];
    __shared__ float sv[K_];
    __shared__ int   si[K_];

    const int t = threadIdx.x;
    const int b = blockIdx.x;
    float* zrow = z + (size_t)b * DSAE;

    float v[64];
    float lmax = -FLT_MAX; int lidx = t;
    #pragma unroll
    for (int i = 0; i < 64; ++i) {
        v[i] = zrow[t + (i << 8)];
        if (v[i] > lmax) { lmax = v[i]; lidx = t + (i << 8); }
    }

    for (int k = 0; k < K_; ++k) {
        // wave-level argmax (value desc, index asc on ties)
        float m = lmax; int mi = lidx;
        #pragma unroll
        for (int off = 1; off < 64; off <<= 1) {
            float ov = __shfl_xor(m,  off, 64);
            int   oi = __shfl_xor(mi, off, 64);
            if (ov > m || (ov == m && oi < mi)) { m = ov; mi = oi; }
        }
        if ((t & 63) == 0) { wv[t >> 6] = m; wi[t >> 6] = mi; }
        __syncthreads();
        float gv = wv[0]; int gi = wi[0];
        #pragma unroll
        for (int w = 1; w < 4; ++w) {
            float ov = wv[w]; int oi = wi[w];
            if (ov > gv || (ov == gv && oi < gi)) { gv = ov; gi = oi; }
        }
        if (t == 0) { sv[k] = gv; si[k] = gi; }
        if ((gi & 255) == t) {                    // owner: mark + rescan its 64 slots
            lmax = -FLT_MAX; lidx = t;
            #pragma unroll
            for (int i = 0; i < 64; ++i) {
                if (t + (i << 8) == gi) v[i] = -FLT_MAX;
                if (v[i] > lmax) { lmax = v[i]; lidx = t + (i << 8); }
            }
        }
        __syncthreads();
    }

    // rebuild z: zeros everywhere, relu(val) at the K selected slots
    #pragma unroll
    for (int i = 0; i < 64; ++i) zrow[t + (i << 8)] = 0.f;
    __syncthreads();
    if (t < K_) {
        float val = sv[t] > 0.f ? sv[t] : 0.f;
        zrow[si[t]] = val;
        sel_val[b * K_ + t] = val;
        sel_idx[b * K_ + t] = si[t];
    }
}

// ---------------- Kernel 4: sparse decode + fused sq-err partial ----------------
// grid = 32 b x 12 chunks (1024 floats each); thread owns 4 consecutive floats
__global__ __launch_bounds__(256, 4) void decode_kernel(
    const float* __restrict__ W_dec,   // (DSAE x TD)
    const float* __restrict__ b_dec,   // (TD)
    const float* __restrict__ x,       // (32 x TD)
    const float* __restrict__ sel_val,
    const int*   __restrict__ sel_idx,
    float* __restrict__ xhat,          // d_out + 1 (unaligned base -> scalar stores)
    float* __restrict__ partial)
{
    __shared__ float sv[K_];
    __shared__ int   si[K_];
    __shared__ float wsum[4];

    const int t     = threadIdx.x;
    const int blk   = blockIdx.x;
    const int b     = blk / 12;
    const int chunk = blk - b * 12;

    if (t < K_) { sv[t] = sel_val[b * K_ + t]; si[t] = sel_idx[b * K_ + t]; }
    __syncthreads();

    const int e = chunk * 1024 + t * 4;          // within TD
    float4 acc = *(const float4*)&b_dec[e];
    #pragma unroll 4
    for (int j = 0; j < K_; ++j) {
        float val = sv[j];
        const float4 w = *(const float4*)&W_dec[(size_t)si[j] * TD + e];
        acc.x += val * w.x;
        acc.y += val * w.y;
        acc.z += val * w.z;
        acc.w += val * w.w;
    }

    const size_t xo = (size_t)b * TD + e;
    xhat[xo + 0] = acc.x;
    xhat[xo + 1] = acc.y;
    xhat[xo + 2] = acc.z;
    xhat[xo + 3] = acc.w;

    const float4 xv = *(const float4*)&x[xo];
    float dx = acc.x - xv.x, dy = acc.y - xv.y;
    float dz = acc.z - xv.z, dw = acc.w - xv.w;
    float ss = dx * dx + dy * dy + dz * dz + dw * dw;
    #pragma unroll
    for (int off = 32; off > 0; off >>= 1) ss += __shfl_down(ss, off, 64);
    if ((t & 63) == 0) wsum[t >> 6] = ss;
    __syncthreads();
    if (t == 0) partial[blk] = wsum[0] + wsum[1] + wsum[2] + wsum[3];
}

// ---------------- Kernel 5: deterministic final loss reduce ----------------
__global__ __launch_bounds__(256) void loss_kernel(const float* __restrict__ partial,
                                                   float* __restrict__ out) {
    __shared__ float wsum[4];
    const int t = threadIdx.x;
    float s = 0.f;
    for (int i = t; i < 384; i += 256) s += partial[i];
    #pragma unroll
    for (int off = 32; off > 0; off >>= 1) s += __shfl_down(s, off, 64);
    if ((t & 63) == 0) wsum[t >> 6] = s;
    __syncthreads();
    if (t == 0) out[0] = (wsum[0] + wsum[1] + wsum[2] + wsum[3]) * (1.0f / 512.0f);
}

extern "C" void kernel_launch(void* const* d_in, const int* in_sizes, int n_in,
                              void* d_out, int out_size, void* d_ws, size_t ws_size,
                              hipStream_t stream) {
    const float* x      = (const float*)d_in[0];
    const float* conv_w = (const float*)d_in[1];
    const float* b_enc  = (const float*)d_in[2];
    const float* W_dec  = (const float*)d_in[3];
    const float* b_dec  = (const float*)d_in[4];

    float* out  = (float*)d_out;
    float* xhat = out + 1;                        // (32,16,768)
    float* z    = out + 1 + 393216;               // (32,16384)

    // A_T scratch lives in the (not yet written) xhat region, 16B-aligned:
    // occupies out[4 .. 4+73728) ⊂ xhat region; consumed by enc_gemm before decode runs.
    float* A_T = out + 4;

    float* sel_val = (float*)d_ws;                               // 32*32 f32
    int*   sel_idx = (int*)((char*)d_ws + 4096);                 // 32*32 i32
    float* partial = (float*)((char*)d_ws + 8192);               // 384 f32

    prep_kernel   <<<96,  256, 0, stream>>>(x, A_T);
    enc_gemm_kernel<<<512, 256, 0, stream>>>(conv_w, A_T, b_enc, z);
    topk_kernel   <<<32,  256, 0, stream>>>(z, sel_val, sel_idx);
    decode_kernel <<<384, 256, 0, stream>>>(W_dec, b_dec, x, sel_val, sel_idx, xhat, partial);
    loss_kernel   <<<1,   256, 0, stream>>>(partial, out);
}

// Round 2
// 146.464 us; speedup vs baseline: 1.3331x; 1.3331x over previous
//
#include <hip/hip_runtime.h>
#include <hip/hip_bf16.h>
#include <float.h>

#define B_    32
#define T_    16
#define DIN   768
#define DSAE  16384
#define K_    32
#define KTOT  2304   // DIN*3
#define KC    64
#define SB    128    // s-rows per enc block
#define KSPLIT 4
#define KLEN  (KTOT / KSPLIT)   // 576 = 9 chunks of 64
#define TD    12288  // T_*DIN

// ---------------- Kernel 1: prep — build A_T[k][b], k = d*3+j ----------------
// u0 = S - x[b,15,d] ; u1 = S ; u2 = S - x[b,0,d]   (S = sum_t x[b,t,d])
__global__ __launch_bounds__(256) void prep_kernel(const float* __restrict__ x,
                                                   float* __restrict__ A_T) {
    int g = blockIdx.x * 256 + threadIdx.x;      // 0..24575
    int b = g / DIN;
    int d = g - b * DIN;
    const float* xp = x + (size_t)b * TD + d;
    float S = 0.f;
    float x0 = xp[0];
    float xl = xp[15 * DIN];
    #pragma unroll
    for (int t = 0; t < T_; ++t) S += xp[t * DIN];
    int base = d * 96 + b;                       // (d*3+j)*32 + b
    A_T[base]      = S - xl;                     // j=0
    A_T[base + 32] = S;                          // j=1
    A_T[base + 64] = S - x0;                     // j=2
}

// ---------------- Kernel 2: encode GEMM, K-split x4 ----------------
// grid = 128 s-tiles x 4 k-splits. block: 256 thr, tile 128s x 32b.
// thread: sl=tid&31, bg=tid>>5; owns s = s0+sl+32m (m 0..3), b = 4bg..4bg+3.
// per kk: 4 conflict-free ds_read_b32 + 1 broadcast ds_read_b128 + 16 FMA.
__global__ __launch_bounds__(256, 2) void enc_gemm_kernel(
    const float* __restrict__ W,      // conv_w flattened (DSAE x KTOT)
    const float* __restrict__ A_T,    // (KTOT x 32)
    float* __restrict__ partial)      // (KSPLIT x 32 x DSAE)
{
    __shared__ float  Wt[SB * 65];    // [s][k] pad 65; bank(s*65+kk) = (s+kk)%32
    __shared__ float4 At4[KC * 8];    // [kk][b/4]

    const int tid = threadIdx.x;
    const int ks   = blockIdx.x & 3;
    const int s0   = (blockIdx.x >> 2) * SB;
    const int koff = ks * KLEN;
    const int sl  = tid & 31;
    const int bg  = tid >> 5;         // 0..7

    float4 acc0 = {0,0,0,0}, acc1 = {0,0,0,0}, acc2 = {0,0,0,0}, acc3 = {0,0,0,0};

    for (int kc = 0; kc < KLEN; kc += KC) {
        __syncthreads();
        // stage W tile: 128 rows x 64 k (8 float4/thread, coalesced 256B runs)
        #pragma unroll
        for (int i = 0; i < 8; ++i) {
            int f4  = tid + 256 * i;              // 0..2047
            int row = f4 >> 4;                    // 16 float4 per row
            int c4  = (f4 & 15) << 2;
            float4 v = *(const float4*)&W[(size_t)(s0 + row) * KTOT + koff + kc + c4];
            float* wp = &Wt[row * 65 + c4];
            wp[0] = v.x; wp[1] = v.y; wp[2] = v.z; wp[3] = v.w;  // 2-way alias only
        }
        // stage A tile: 64 kk x 32 b (already [k][b] layout, straight copy)
        {
            const float4* src = (const float4*)&A_T[(koff + kc) * 32];
            At4[tid]       = src[tid];
            At4[tid + 256] = src[tid + 256];
        }
        __syncthreads();

        #pragma unroll 16
        for (int kk = 0; kk < KC; ++kk) {
            float4 a  = At4[kk * 8 + bg];         // 2 addrs/wave -> broadcast
            float  w0 = Wt[(sl      ) * 65 + kk]; // banks (sl+kk)%32: all distinct
            float  w1 = Wt[(sl +  32) * 65 + kk];
            float  w2 = Wt[(sl +  64) * 65 + kk];
            float  w3 = Wt[(sl +  96) * 65 + kk];
            acc0.x += w0 * a.x; acc0.y += w0 * a.y; acc0.z += w0 * a.z; acc0.w += w0 * a.w;
            acc1.x += w1 * a.x; acc1.y += w1 * a.y; acc1.z += w1 * a.z; acc1.w += w1 * a.w;
            acc2.x += w2 * a.x; acc2.y += w2 * a.y; acc2.z += w2 * a.z; acc2.w += w2 * a.w;
            acc3.x += w3 * a.x; acc3.y += w3 * a.y; acc3.z += w3 * a.z; acc3.w += w3 * a.w;
        }
    }

    // partial[ks][b][s]
    float* pb = partial + (size_t)ks * 32 * DSAE;
    const int b0 = bg * 4;
    #pragma unroll
    for (int j = 0; j < 4; ++j) {
        float* row = pb + (size_t)(b0 + j) * DSAE + s0 + sl;
        float v0 = j == 0 ? acc0.x : j == 1 ? acc0.y : j == 2 ? acc0.z : acc0.w;
        float v1 = j == 0 ? acc1.x : j == 1 ? acc1.y : j == 2 ? acc1.z : acc1.w;
        float v2 = j == 0 ? acc2.x : j == 1 ? acc2.y : j == 2 ? acc2.z : acc2.w;
        float v3 = j == 0 ? acc3.x : j == 1 ? acc3.y : j == 2 ? acc3.z : acc3.w;
        row[0]  = v0;
        row[32] = v1;
        row[64] = v2;
        row[96] = v3;
    }
}

// ---------------- Kernel 2b: combine K-split partials + bias ----------------
__global__ __launch_bounds__(256) void combine_kernel(const float* __restrict__ partial,
                                                      const float* __restrict__ b_enc,
                                                      float* __restrict__ pre) {
    int g  = blockIdx.x * 256 + threadIdx.x;     // float4 index, 0..131071
    int b  = g >> 12;                            // 4096 float4 per row
    int s4 = g & 4095;
    const float4* p = (const float4*)partial;
    float4 acc = p[(size_t)b * 4096 + s4];
    #pragma unroll
    for (int ks = 1; ks < KSPLIT; ++ks) {
        float4 v = p[(size_t)(ks * 32 + b) * 4096 + s4];
        acc.x += v.x; acc.y += v.y; acc.z += v.z; acc.w += v.w;
    }
    float4 be = ((const float4*)b_enc)[s4];
    acc.x += be.x; acc.y += be.y; acc.z += be.z; acc.w += be.w;
    ((float4*)pre)[(size_t)b * 4096 + s4] = acc;
}

// ---------------- Kernel 3: top-k (iterative argmax, tie-break = lower idx) ----------------
__global__ __launch_bounds__(256, 1) void topk_kernel(
    float* __restrict__ z,            // in: pre row-major (32 x DSAE); out: sparse z
    float* __restrict__ sel_val,
    int*   __restrict__ sel_idx)
{
    __shared__ float wv[4];
    __shared__ int   wi[4];
    __shared__ float sv[K_];
    __shared__ int   si[K_];

    const int t = threadIdx.x;
    const int b = blockIdx.x;
    float* zrow = z + (size_t)b * DSAE;

    float v[64];
    float lmax = -FLT_MAX; int lidx = t;
    #pragma unroll
    for (int i = 0; i < 64; ++i) {
        v[i] = zrow[t + (i << 8)];
        if (v[i] > lmax) { lmax = v[i]; lidx = t + (i << 8); }
    }

    for (int k = 0; k < K_; ++k) {
        float m = lmax; int mi = lidx;
        #pragma unroll
        for (int off = 1; off < 64; off <<= 1) {
            float ov = __shfl_xor(m,  off, 64);
            int   oi = __shfl_xor(mi, off, 64);
            if (ov > m || (ov == m && oi < mi)) { m = ov; mi = oi; }
        }
        if ((t & 63) == 0) { wv[t >> 6] = m; wi[t >> 6] = mi; }
        __syncthreads();
        float gv = wv[0]; int gi = wi[0];
        #pragma unroll
        for (int w = 1; w < 4; ++w) {
            float ov = wv[w]; int oi = wi[w];
            if (ov > gv || (ov == gv && oi < gi)) { gv = ov; gi = oi; }
        }
        if (t == 0) { sv[k] = gv; si[k] = gi; }
        if ((gi & 255) == t) {                    // owner: mark + rescan
            lmax = -FLT_MAX; lidx = t;
            #pragma unroll
            for (int i = 0; i < 64; ++i) {
                if (t + (i << 8) == gi) v[i] = -FLT_MAX;
                if (v[i] > lmax) { lmax = v[i]; lidx = t + (i << 8); }
            }
        }
        __syncthreads();
    }

    #pragma unroll
    for (int i = 0; i < 64; ++i) zrow[t + (i << 8)] = 0.f;
    __syncthreads();
    if (t < K_) {
        float val = sv[t] > 0.f ? sv[t] : 0.f;
        zrow[si[t]] = val;
        sel_val[b * K_ + t] = val;
        sel_idx[b * K_ + t] = si[t];
    }
}

// ---------------- Kernel 4: sparse decode + fused sq-err partial ----------------
__global__ __launch_bounds__(256, 4) void decode_kernel(
    const float* __restrict__ W_dec,   // (DSAE x TD)
    const float* __restrict__ b_dec,   // (TD)
    const float* __restrict__ x,       // (32 x TD)
    const float* __restrict__ sel_val,
    const int*   __restrict__ sel_idx,
    float* __restrict__ xhat,          // d_out + 1
    float* __restrict__ partial)
{
    __shared__ float sv[K_];
    __shared__ int   si[K_];
    __shared__ float wsum[4];

    const int t     = threadIdx.x;
    const int blk   = blockIdx.x;
    const int b     = blk / 12;
    const int chunk = blk - b * 12;

    if (t < K_) { sv[t] = sel_val[b * K_ + t]; si[t] = sel_idx[b * K_ + t]; }
    __syncthreads();

    const int e = chunk * 1024 + t * 4;          // within TD
    float4 acc = *(const float4*)&b_dec[e];
    #pragma unroll 8
    for (int j = 0; j < K_; ++j) {
        float val = sv[j];
        const float4 w = *(const float4*)&W_dec[(size_t)si[j] * TD + e];
        acc.x += val * w.x;
        acc.y += val * w.y;
        acc.z += val * w.z;
        acc.w += val * w.w;
    }

    const size_t xo = (size_t)b * TD + e;
    xhat[xo + 0] = acc.x;
    xhat[xo + 1] = acc.y;
    xhat[xo + 2] = acc.z;
    xhat[xo + 3] = acc.w;

    const float4 xv = *(const float4*)&x[xo];
    float dx = acc.x - xv.x, dy = acc.y - xv.y;
    float dz = acc.z - xv.z, dw = acc.w - xv.w;
    float ss = dx * dx + dy * dy + dz * dz + dw * dw;
    #pragma unroll
    for (int off = 32; off > 0; off >>= 1) ss += __shfl_down(ss, off, 64);
    if ((t & 63) == 0) wsum[t >> 6] = ss;
    __syncthreads();
    if (t == 0) partial[blk] = wsum[0] + wsum[1] + wsum[2] + wsum[3];
}

// ---------------- Kernel 5: deterministic final loss reduce ----------------
__global__ __launch_bounds__(256) void loss_kernel(const float* __restrict__ partial,
                                                   float* __restrict__ out) {
    __shared__ float wsum[4];
    const int t = threadIdx.x;
    float s = 0.f;
    for (int i = t; i < 384; i += 256) s += partial[i];
    #pragma unroll
    for (int off = 32; off > 0; off >>= 1) s += __shfl_down(s, off, 64);
    if ((t & 63) == 0) wsum[t >> 6] = s;
    __syncthreads();
    if (t == 0) out[0] = (wsum[0] + wsum[1] + wsum[2] + wsum[3]) * (1.0f / 512.0f);
}

extern "C" void kernel_launch(void* const* d_in, const int* in_sizes, int n_in,
                              void* d_out, int out_size, void* d_ws, size_t ws_size,
                              hipStream_t stream) {
    const float* x      = (const float*)d_in[0];
    const float* conv_w = (const float*)d_in[1];
    const float* b_enc  = (const float*)d_in[2];
    const float* W_dec  = (const float*)d_in[3];
    const float* b_dec  = (const float*)d_in[4];

    float* out  = (float*)d_out;
    float* xhat = out + 1;                        // (32,16,768)
    float* z    = out + 1 + 393216;               // (32,16384)

    // ws layout (ws is large; harness poisons it, we overwrite what we use)
    float* partial_enc  = (float*)d_ws;                               // 8 MB
    float* A_T          = (float*)((char*)d_ws + (8u << 20));         // 288 KB
    float* sel_val      = (float*)((char*)d_ws + (8u << 20) + 304 * 1024);
    int*   sel_idx      = (int*)  ((char*)d_ws + (8u << 20) + 308 * 1024);
    float* partial_loss = (float*)((char*)d_ws + (8u << 20) + 312 * 1024);

    prep_kernel    <<<96,  256, 0, stream>>>(x, A_T);
    enc_gemm_kernel<<<512, 256, 0, stream>>>(conv_w, A_T, partial_enc);
    combine_kernel <<<512, 256, 0, stream>>>(partial_enc, b_enc, z);
    topk_kernel    <<<32,  256, 0, stream>>>(z, sel_val, sel_idx);
    decode_kernel  <<<384, 256, 0, stream>>>(W_dec, b_dec, x, sel_val, sel_idx, xhat, partial_loss);
    loss_kernel    <<<1,   256, 0, stream>>>(partial_loss, out);
}

// Round 3
// 143.634 us; speedup vs baseline: 1.3593x; 1.0197x over previous
//
#include <hip/hip_runtime.h>
#include <hip/hip_bf16.h>
#include <float.h>

#define B_    32
#define T_    16
#define DIN   768
#define DSAE  16384
#define K_    32
#define KTOT  2304   // DIN*3
#define TD    12288  // T_*DIN

#define KSPLIT 8
#define KLEN   288   // KTOT/KSPLIT
#define KC     32    // k per staged chunk
#define NCH    9     // KLEN/KC
#define SB     512   // s-rows per enc block
#define WSTR   36    // Wt padded stride in floats (pad 4 -> conflict-free b128)

// ---------------- Kernel 1: prep — build A_T[k][b], k = d*3+j ----------------
// u0 = S - x[b,15,d] ; u1 = S ; u2 = S - x[b,0,d]   (S = sum_t x[b,t,d])
__global__ __launch_bounds__(256) void prep_kernel(const float* __restrict__ x,
                                                   float* __restrict__ A_T) {
    int g = blockIdx.x * 256 + threadIdx.x;      // 0..24575
    int b = g / DIN;
    int d = g - b * DIN;
    const float* xp = x + (size_t)b * TD + d;
    float S = 0.f;
    float x0 = xp[0];
    float xl = xp[15 * DIN];
    #pragma unroll
    for (int t = 0; t < T_; ++t) S += xp[t * DIN];
    int base = d * 96 + b;                       // (d*3+j)*32 + b
    A_T[base]      = S - xl;                     // j=0
    A_T[base + 32] = S;                          // j=1
    A_T[base + 64] = S - x0;                     // j=2
}

// ---------------- Kernel 2: encode GEMM (8s x 8b x 4kk register tile) ----------------
// grid = 32 s-tiles x 8 k-splits; 256 thr; block tile 512s x 32b.
// wave w = tid>>6 owns b = 8w..8w+7; lane l owns s = s0 + l + 64m (m 0..7).
// All LDS reads are b128; W reads conflict-free via stride-36 pad; A reads wave-uniform.
#define FMA4(ACC, S, A) { ACC.x += (S) * (A).x; ACC.y += (S) * (A).y; \
                          ACC.z += (S) * (A).z; ACC.w += (S) * (A).w; }

__global__ __launch_bounds__(256, 1) void enc_gemm_kernel(
    const float* __restrict__ W,      // conv_w flattened (DSAE x KTOT)
    const float* __restrict__ A_T,    // (KTOT x 32)
    float* __restrict__ partial)      // (KSPLIT x 32 x DSAE)
{
    __shared__ float  Wt[SB * WSTR];  // 73728 B
    __shared__ float4 At4[KC * 8];    // [kk][b/4], 4096 B

    const int tid  = threadIdx.x;
    const int ks   = blockIdx.x & 7;
    const int s0   = (blockIdx.x >> 3) * SB;
    const int koff = ks * KLEN;
    const int l    = tid & 63;
    const int w    = tid >> 6;

    float4 acc0[8], acc1[8];
    #pragma unroll
    for (int m = 0; m < 8; ++m) {
        acc0[m] = make_float4(0.f, 0.f, 0.f, 0.f);
        acc1[m] = make_float4(0.f, 0.f, 0.f, 0.f);
    }

    float4 wreg[16];
    float4 areg;

    // prologue: load chunk 0 into registers
    #pragma unroll
    for (int i = 0; i < 16; ++i) {
        int f4 = tid + (i << 8);
        int row = f4 >> 3, c = (f4 & 7) << 2;
        wreg[i] = *(const float4*)&W[(size_t)(s0 + row) * KTOT + koff + c];
    }
    areg = ((const float4*)&A_T[koff * 32])[tid];

    #pragma unroll 1
    for (int ch = 0; ch < NCH; ++ch) {
        __syncthreads();                          // previous compute finished
        #pragma unroll
        for (int i = 0; i < 16; ++i) {
            int f4 = tid + (i << 8);
            int row = f4 >> 3, c = (f4 & 7) << 2;
            *(float4*)&Wt[row * WSTR + c] = wreg[i];
        }
        At4[tid] = areg;
        __syncthreads();

        if (ch + 1 < NCH) {                       // prefetch next chunk (flies under compute)
            const int kc = (ch + 1) * KC;
            #pragma unroll
            for (int i = 0; i < 16; ++i) {
                int f4 = tid + (i << 8);
                int row = f4 >> 3, c = (f4 & 7) << 2;
                wreg[i] = *(const float4*)&W[(size_t)(s0 + row) * KTOT + koff + kc + c];
            }
            areg = ((const float4*)&A_T[(koff + kc) * 32])[tid];
        }

        #pragma unroll
        for (int g = 0; g < 8; ++g) {
            const int kk0 = g << 2;
            float4 a0[4], a1[4];
            #pragma unroll
            for (int d = 0; d < 4; ++d) {
                a0[d] = At4[(kk0 + d) * 8 + (w << 1)];
                a1[d] = At4[(kk0 + d) * 8 + (w << 1) + 1];
            }
            #pragma unroll
            for (int m = 0; m < 8; ++m) {
                float4 wv = *(const float4*)&Wt[(l + (m << 6)) * WSTR + kk0];
                FMA4(acc0[m], wv.x, a0[0]); FMA4(acc0[m], wv.y, a0[1]);
                FMA4(acc0[m], wv.z, a0[2]); FMA4(acc0[m], wv.w, a0[3]);
                FMA4(acc1[m], wv.x, a1[0]); FMA4(acc1[m], wv.y, a1[1]);
                FMA4(acc1[m], wv.z, a1[2]); FMA4(acc1[m], wv.w, a1[3]);
            }
        }
    }

    // epilogue: partial[ks][b][s], coalesced over l
    float* pb = partial + (size_t)(ks * 32 + (w << 3)) * DSAE + s0 + l;
    #pragma unroll
    for (int m = 0; m < 8; ++m) {
        const int so = m << 6;
        pb[(size_t)0 * DSAE + so] = acc0[m].x;
        pb[(size_t)1 * DSAE + so] = acc0[m].y;
        pb[(size_t)2 * DSAE + so] = acc0[m].z;
        pb[(size_t)3 * DSAE + so] = acc0[m].w;
        pb[(size_t)4 * DSAE + so] = acc1[m].x;
        pb[(size_t)5 * DSAE + so] = acc1[m].y;
        pb[(size_t)6 * DSAE + so] = acc1[m].z;
        pb[(size_t)7 * DSAE + so] = acc1[m].w;
    }
}

// ---------------- Kernel 2b: combine K-split partials + bias ----------------
__global__ __launch_bounds__(256) void combine_kernel(const float* __restrict__ partial,
                                                      const float* __restrict__ b_enc,
                                                      float* __restrict__ pre) {
    int g  = blockIdx.x * 256 + threadIdx.x;     // float4 index, 0..131071
    int b  = g >> 12;                            // 4096 float4 per row
    int s4 = g & 4095;
    const float4* p = (const float4*)partial;
    float4 acc = p[(size_t)b * 4096 + s4];
    #pragma unroll
    for (int ks = 1; ks < KSPLIT; ++ks) {
        float4 v = p[(size_t)(ks * 32 + b) * 4096 + s4];
        acc.x += v.x; acc.y += v.y; acc.z += v.z; acc.w += v.w;
    }
    float4 be = ((const float4*)b_enc)[s4];
    acc.x += be.x; acc.y += be.y; acc.z += be.z; acc.w += be.w;
    ((float4*)pre)[(size_t)b * 4096 + s4] = acc;
}

// ---------------- Kernel 3: top-k via 4-pass radix select ----------------
// one block (1024 thr) per batch row; exact lax.top_k semantics
// (k largest values, ties broken by ascending index).
__global__ __launch_bounds__(1024, 1) void topk_kernel(
    float* __restrict__ z,            // in: pre (32 x DSAE); out: sparse z
    float* __restrict__ sel_val,
    int*   __restrict__ sel_idx)
{
    __shared__ unsigned hist[256];
    __shared__ unsigned gsfx[65];
    __shared__ unsigned sfx[257];
    __shared__ int      sdelta;
    __shared__ unsigned scnt;
    __shared__ int      l_idx[K_];
    __shared__ float    l_val[K_];
    __shared__ int      eq_min;

    const int t = threadIdx.x;
    const int b = blockIdx.x;
    float* zrow = z + (size_t)b * DSAE;

    float v[16]; unsigned u[16];
    #pragma unroll
    for (int i = 0; i < 16; ++i) {
        float f = zrow[t + (i << 10)];
        v[i] = f;
        unsigned x = __float_as_uint(f);
        u[i] = (x & 0x80000000u) ? ~x : (x | 0x80000000u);   // monotone map
    }

    unsigned prefix = 0, pmask = 0;
    int need = K_;

    for (int p = 0; p < 4; ++p) {
        const int shift = 24 - 8 * p;
        if (t < 256) hist[t] = 0;
        __syncthreads();
        #pragma unroll
        for (int i = 0; i < 16; ++i)
            if ((u[i] & pmask) == prefix)
                atomicAdd(&hist[(u[i] >> shift) & 255u], 1u);
        __syncthreads();
        if (t < 64) {                                        // wave0 group-suffix scan
            unsigned s4 = hist[4*t] + hist[4*t+1] + hist[4*t+2] + hist[4*t+3];
            #pragma unroll
            for (int off = 1; off < 64; off <<= 1) {
                unsigned o = __shfl_down(s4, off, 64);
                if (t + off < 64) s4 += o;
            }
            gsfx[t] = s4;
            if (t == 0) gsfx[64] = 0;
        }
        __syncthreads();
        if (t < 256) {                                       // per-bin suffix sums
            int q = t >> 2;
            unsigned acc = gsfx[q + 1];
            for (int d = 4*q + 3; d >= t; --d) acc += hist[d];
            sfx[t] = acc;
            if (t == 0) sfx[256] = 0;
        }
        __syncthreads();
        if (t < 256) {
            if (sfx[t] >= (unsigned)need && sfx[t + 1] < (unsigned)need) sdelta = t;
        }
        __syncthreads();
        const int dlt = sdelta;
        need  -= (int)sfx[dlt + 1];
        prefix |= ((unsigned)dlt) << shift;
        pmask  |= 0xFFu << shift;
        __syncthreads();
    }

    const unsigned ustar = prefix;                // exact 32nd-largest (mapped) value
    if (t == 0) scnt = 0;
    __syncthreads();

    unsigned eqmask = 0;
    #pragma unroll
    for (int i = 0; i < 16; ++i) {
        int idx = t + (i << 10);
        if (u[i] > ustar) {
            unsigned s = atomicAdd(&scnt, 1u);
            l_idx[s] = idx; l_val[s] = v[i];
        } else if (u[i] == ustar) {
            eqmask |= (1u << i);
        }
    }
    __syncthreads();
    const int needf = need;                       // take needf equals, smallest index first
    for (int r = 0; r < needf; ++r) {
        if (t == 0) eq_min = 0x7FFFFFFF;
        __syncthreads();
        #pragma unroll
        for (int i = 0; i < 16; ++i)
            if (eqmask & (1u << i)) atomicMin(&eq_min, t + (i << 10));
        __syncthreads();
        #pragma unroll
        for (int i = 0; i < 16; ++i)
            if ((eqmask & (1u << i)) && (t + (i << 10) == eq_min)) {
                eqmask &= ~(1u << i);
                unsigned s = atomicAdd(&scnt, 1u);
                l_idx[s] = eq_min; l_val[s] = v[i];
            }
        __syncthreads();
    }

    // zero row (vals already in regs), then deterministic scatter
    #pragma unroll
    for (int i = 0; i < 16; ++i) zrow[t + (i << 10)] = 0.f;
    __syncthreads();
    if (t == 0) {                                 // sort 32 by idx asc (deterministic order)
        for (int a = 1; a < K_; ++a) {
            int ia = l_idx[a]; float va = l_val[a]; int c = a - 1;
            while (c >= 0 && l_idx[c] > ia) {
                l_idx[c+1] = l_idx[c]; l_val[c+1] = l_val[c]; --c;
            }
            l_idx[c+1] = ia; l_val[c+1] = va;
        }
    }
    __syncthreads();
    if (t < K_) {
        float val = l_val[t] > 0.f ? l_val[t] : 0.f;
        zrow[l_idx[t]] = val;
        sel_val[b * K_ + t] = val;
        sel_idx[b * K_ + t] = l_idx[t];
    }
}

// ---------------- Kernel 4: sparse decode + fused sq-err partial ----------------
__global__ __launch_bounds__(256, 4) void decode_kernel(
    const float* __restrict__ W_dec,   // (DSAE x TD)
    const float* __restrict__ b_dec,   // (TD)
    const float* __restrict__ x,       // (32 x TD)
    const float* __restrict__ sel_val,
    const int*   __restrict__ sel_idx,
    float* __restrict__ xhat,          // d_out + 1
    float* __restrict__ partial)
{
    __shared__ float sv[K_];
    __shared__ int   si[K_];
    __shared__ float wsum[4];

    const int t     = threadIdx.x;
    const int blk   = blockIdx.x;
    const int b     = blk / 12;
    const int chunk = blk - b * 12;

    if (t < K_) { sv[t] = sel_val[b * K_ + t]; si[t] = sel_idx[b * K_ + t]; }
    __syncthreads();

    const int e = chunk * 1024 + t * 4;          // within TD
    float4 acc = *(const float4*)&b_dec[e];
    #pragma unroll 8
    for (int j = 0; j < K_; ++j) {
        float val = sv[j];
        const float4 w = *(const float4*)&W_dec[(size_t)si[j] * TD + e];
        acc.x += val * w.x;
        acc.y += val * w.y;
        acc.z += val * w.z;
        acc.w += val * w.w;
    }

    const size_t xo = (size_t)b * TD + e;
    xhat[xo + 0] = acc.x;
    xhat[xo + 1] = acc.y;
    xhat[xo + 2] = acc.z;
    xhat[xo + 3] = acc.w;

    const float4 xv = *(const float4*)&x[xo];
    float dx = acc.x - xv.x, dy = acc.y - xv.y;
    float dz = acc.z - xv.z, dw = acc.w - xv.w;
    float ss = dx * dx + dy * dy + dz * dz + dw * dw;
    #pragma unroll
    for (int off = 32; off > 0; off >>= 1) ss += __shfl_down(ss, off, 64);
    if ((t & 63) == 0) wsum[t >> 6] = ss;
    __syncthreads();
    if (t == 0) partial[blk] = wsum[0] + wsum[1] + wsum[2] + wsum[3];
}

// ---------------- Kernel 5: deterministic final loss reduce ----------------
__global__ __launch_bounds__(256) void loss_kernel(const float* __restrict__ partial,
                                                   float* __restrict__ out) {
    __shared__ float wsum[4];
    const int t = threadIdx.x;
    float s = 0.f;
    for (int i = t; i < 384; i += 256) s += partial[i];
    #pragma unroll
    for (int off = 32; off > 0; off >>= 1) s += __shfl_down(s, off, 64);
    if ((t & 63) == 0) wsum[t >> 6] = s;
    __syncthreads();
    if (t == 0) out[0] = (wsum[0] + wsum[1] + wsum[2] + wsum[3]) * (1.0f / 512.0f);
}

extern "C" void kernel_launch(void* const* d_in, const int* in_sizes, int n_in,
                              void* d_out, int out_size, void* d_ws, size_t ws_size,
                              hipStream_t stream) {
    const float* x      = (const float*)d_in[0];
    const float* conv_w = (const float*)d_in[1];
    const float* b_enc  = (const float*)d_in[2];
    const float* W_dec  = (const float*)d_in[3];
    const float* b_dec  = (const float*)d_in[4];

    float* out  = (float*)d_out;
    float* xhat = out + 1;                        // (32,16,768)
    float* z    = out + 1 + 393216;               // (32,16384) — also holds pre

    // ws layout
    float* partial_enc  = (float*)d_ws;                               // 16.8 MB
    float* A_T          = (float*)((char*)d_ws + (20u << 20));        // 288 KB
    float* sel_val      = (float*)((char*)d_ws + (21u << 20));
    int*   sel_idx      = (int*)  ((char*)d_ws + (21u << 20) + 4096);
    float* partial_loss = (float*)((char*)d_ws + (21u << 20) + 8192);

    prep_kernel    <<<96,  256,  0, stream>>>(x, A_T);
    enc_gemm_kernel<<<256, 256,  0, stream>>>(conv_w, A_T, partial_enc);
    combine_kernel <<<512, 256,  0, stream>>>(partial_enc, b_enc, z);
    topk_kernel    <<<32,  1024, 0, stream>>>(z, sel_val, sel_idx);
    decode_kernel  <<<384, 256,  0, stream>>>(W_dec, b_dec, x, sel_val, sel_idx, xhat, partial_loss);
    loss_kernel    <<<1,   256,  0, stream>>>(partial_loss, out);
}